// Round 13
// baseline (359.270 us; speedup 1.0000x reference)
//
#include <hip/hip_runtime.h>

typedef unsigned short u16;
typedef unsigned int u32;
typedef unsigned long long u64;

// B=2, L=2048, D=512, H=8, DK=DV=64, M=B*L=4096
// All GEMMs: C[M,N] = A[M,K] @ Bt[N,K]^T, bf16 inputs, f32 MFMA accum.

typedef __attribute__((ext_vector_type(8))) short bf16x8;
typedef __attribute__((ext_vector_type(4))) float f32x4;
typedef __attribute__((ext_vector_type(4))) u32 u32x4;

__device__ __forceinline__ u16 f2bf(float f) {
  u32 x = __float_as_uint(f);
  return (u16)((x + 0x7FFFu + ((x >> 16) & 1u)) >> 16);  // RNE
}
__device__ __forceinline__ u32 pk2(float a, float b) {
  return (u32)f2bf(a) | ((u32)f2bf(b) << 16);
}
__device__ __forceinline__ bf16x8 negv(bf16x8 v) {
  u32x4 x = __builtin_bit_cast(u32x4, v);
  x ^= 0x80008000u;
  return __builtin_bit_cast(bf16x8, x);
}

// ---------------- prep: pack_mask + pack_a3 + pack_bt + zero_stats ----------
__global__ __launch_bounds__(256) void prep(
    const float* __restrict__ qr, const float* __restrict__ qi,
    const float* __restrict__ kr, const float* __restrict__ ki,
    const float* __restrict__ vr, const float* __restrict__ vi,
    const float* __restrict__ wqr, const float* __restrict__ wqi,
    const float* __restrict__ wkr, const float* __restrict__ wki,
    const float* __restrict__ wvr, const float* __restrict__ wvi,
    const float* __restrict__ wor, const float* __restrict__ woi,
    const int* __restrict__ mask,
    u16* __restrict__ A, u16* __restrict__ Btb, u64* __restrict__ mb,
    float* __restrict__ stats) {
  __shared__ float tile[64][65];
  int bid = blockIdx.x;
  int t = threadIdx.x;
  if (bid < 32768) {  // ---- pack_mask ----
    int tid = bid * 256 + t;
    u64 bal = __ballot(mask[tid] != 0);
    if ((t & 63) == 0) mb[tid >> 6] = bal;
    return;
  }
  bid -= 32768;
  if (bid < 6144) {  // ---- pack_a3: Aq/Ak/Av [4096][1024] = [xr|xi] ----
    int z = bid >> 11;
    int bx = bid & 2047;
    const float* r  = (z == 0) ? qr : (z == 1) ? kr : vr;
    const float* im = (z == 0) ? qi : (z == 1) ? ki : vi;
    int c = bx * 256 + t;
    int m = c >> 7;
    int ck = (c & 127) * 8;
    const float* s = (ck < 512) ? (r + (size_t)m * 512 + ck)
                                : (im + (size_t)m * 512 + (ck - 512));
    float4 a = ((const float4*)s)[0];
    float4 b = ((const float4*)s)[1];
    uint4 o;
    o.x = pk2(a.x, a.y); o.y = pk2(a.z, a.w);
    o.z = pk2(b.x, b.y); o.w = pk2(b.z, b.w);
    ((uint4*)(A + (size_t)z * 4194304))[c] = o;
    return;
  }
  bid -= 6144;
  if (bid < 1024) {  // ---- pack_bt: Bt[z] [1024 n][1024 k] ----
    int z = bid >> 8;
    int bx = bid & 255;
    const float* wr = (z==0)?wqr:(z==1)?wkr:(z==2)?wvr:wor;
    const float* wi = (z==0)?wqi:(z==1)?wki:(z==2)?wvi:woi;
    u16* Bt = Btb + (size_t)z * 1048576;
    int n0 = (bx >> 4) * 64;
    int k0 = (bx & 15) * 64;
    bool nlow = (n0 < 512), klow = (k0 < 512);
    const float* src = nlow ? (klow ? wr : wi) : (klow ? wi : wr);
    float sgn = (nlow && !klow) ? -1.0f : 1.0f;
    int col0 = nlow ? n0 : n0 - 512;
    int kr0 = klow ? k0 : k0 - 512;
    {
      int rr = t >> 2, cc = (t & 3) * 16;
      const float4* s = (const float4*)(src + (size_t)(kr0 + rr) * 512 + col0 + cc);
#pragma unroll
      for (int j = 0; j < 4; ++j) {
        float4 v = s[j];
        tile[rr][cc + j*4 + 0] = v.x; tile[rr][cc + j*4 + 1] = v.y;
        tile[rr][cc + j*4 + 2] = v.z; tile[rr][cc + j*4 + 3] = v.w;
      }
    }
    __syncthreads();
    {
      int nn = t >> 2, kc = (t & 3) * 16;
      u32 w[8];
#pragma unroll
      for (int j = 0; j < 8; ++j)
        w[j] = pk2(sgn * tile[kc + 2*j][nn], sgn * tile[kc + 2*j + 1][nn]);
      uint4* d = (uint4*)(Bt + (size_t)(n0 + nn) * 1024 + k0 + kc);
      d[0] = make_uint4(w[0], w[1], w[2], w[3]);
      d[1] = make_uint4(w[4], w[5], w[6], w[7]);
    }
    return;
  }
  if (t < 16) stats[t] = 0.0f;
}

// vt [16][128 c][2048 l] bf16 : transposed V (c<64 real, c>=64 imag)
__global__ __launch_bounds__(256) void pack_vt(const u16* __restrict__ Cvm,
                                               u16* __restrict__ vt) {
  int z = blockIdx.y;
  int b = z >> 3, h = z & 7;
  int lt = blockIdx.x >> 1, ct = blockIdx.x & 1;
  int l0 = lt * 64, c0 = ct * 64;
  int n0 = (ct == 0) ? (h * 64) : (512 + h * 64);
  __shared__ u16 tile[64][80];
  int t = threadIdx.x;
  {
    int lr = t >> 2, cc = (t & 3) * 16;
    const uint4* s = (const uint4*)(Cvm + ((size_t)(b * 2048 + l0 + lr)) * 1024 + n0 + cc);
    uint4 v0 = s[0], v1 = s[1];
    *(uint4*)&tile[lr][cc] = v0;
    *(uint4*)&tile[lr][cc + 8] = v1;
  }
  __syncthreads();
  {
    int cr = t >> 2, lc = (t & 3) * 16;
    u32 w[8];
#pragma unroll
    for (int j = 0; j < 8; ++j)
      w[j] = (u32)tile[lc + 2*j][cr] | ((u32)tile[lc + 2*j + 1][cr] << 16);
    uint4* d = (uint4*)(vt + ((size_t)z * 128 + c0 + cr) * 2048 + l0 + lc);
    d[0] = make_uint4(w[0], w[1], w[2], w[3]);
    d[1] = make_uint4(w[4], w[5], w[6], w[7]);
  }
}

// ---------------- async staging via global_load_lds (width 16) ----------------
// XOR-swizzled LDS layout (chunk c of row r at r*64+((c^(r&7))<<3)), built per
// guide rule #21: LINEAR LDS dest (wave base + lane*16B), PRE-SWIZZLED global
// source col = (lane&7) ^ (lane>>3). Fragment reads unchanged.
// 256-thread variants (GEMMs):
__device__ __forceinline__ void glds128(const u16* __restrict__ g, int ld,
                                        u16* lds, int t) {
  int lane = t & 63, w = t >> 6;
  int sub = lane >> 3;
  int cs = (lane & 7) ^ sub;
#pragma unroll
  for (int p = 0; p < 4; ++p) {
    int r = p * 32 + w * 8 + sub;
    const u16* ga = g + (size_t)r * ld + cs * 8;
    u16* la = lds + (size_t)(p * 32 + w * 8) * 64;  // wave-uniform base
    __builtin_amdgcn_global_load_lds(
        (const __attribute__((address_space(1))) void*)ga,
        (__attribute__((address_space(3))) void*)la, 16, 0, 0);
  }
}
// 128-thread variants (attention kernels):
__device__ __forceinline__ void glds64h(const u16* __restrict__ g, int ld,
                                        u16* lds, int t) {
  int lane = t & 63, w = t >> 6;  // w in 0..1
  int sub = lane >> 3;
  int cs = (lane & 7) ^ sub;
#pragma unroll
  for (int p = 0; p < 4; ++p) {
    int r = p * 16 + w * 8 + sub;
    const u16* ga = g + (size_t)r * ld + cs * 8;
    u16* la = lds + (size_t)(p * 16 + w * 8) * 64;
    __builtin_amdgcn_global_load_lds(
        (const __attribute__((address_space(1))) void*)ga,
        (__attribute__((address_space(3))) void*)la, 16, 0, 0);
  }
}
__device__ __forceinline__ void glds128h(const u16* __restrict__ g, int ld,
                                         u16* lds, int t) {
  int lane = t & 63, w = t >> 6;
  int sub = lane >> 3;
  int cs = (lane & 7) ^ sub;
#pragma unroll
  for (int p = 0; p < 8; ++p) {
    int r = p * 16 + w * 8 + sub;
    const u16* ga = g + (size_t)r * ld + cs * 8;
    u16* la = lds + (size_t)(p * 16 + w * 8) * 64;
    __builtin_amdgcn_global_load_lds(
        (const __attribute__((address_space(1))) void*)ga,
        (__attribute__((address_space(3))) void*)la, 16, 0, 0);
  }
}

// ---------------- projection GEMM: C[4096,1024] bf16 = A @ Bt^T (x3 via z) ----------------
__global__ __launch_bounds__(256) void gemm_proj(const u16* __restrict__ Abase,
                                                 const u16* __restrict__ Btbase,
                                                 u16* __restrict__ Cbase) {
  __shared__ u16 lA[128 * 64], lB[128 * 64];
  int t = threadIdx.x, lane = t & 63, wid = t >> 6;
  int c15 = lane & 15, g = lane >> 4, l7 = lane & 7;
  int z = blockIdx.z;
  const u16* A  = Abase  + (size_t)z * 4194304;
  const u16* Bt = Btbase + (size_t)z * 1048576;
  u16* C = Cbase + (size_t)z * 4194304;
  int brow = blockIdx.y * 128, bcol = blockIdx.x * 128;
  float scale = (z == 0) ? 0.125f : 1.0f;  // q / sqrt(DK)
  int sw0 = ((g ^ l7) << 3), sw1 = (((4 | g) ^ l7) << 3);
  int wr0 = (wid >> 1) * 64 + c15, wc0 = (wid & 1) * 64 + c15;
  const u16 *pA0 = lA + wr0 * 64 + sw0, *pA1 = lA + wr0 * 64 + sw1;
  const u16 *pB0 = lB + wc0 * 64 + sw0, *pB1 = lB + wc0 * 64 + sw1;
  f32x4 zero = {0.f, 0.f, 0.f, 0.f};
  f32x4 acc[4][4];
#pragma unroll
  for (int mi = 0; mi < 4; ++mi)
#pragma unroll
    for (int ni = 0; ni < 4; ++ni) acc[mi][ni] = zero;
  for (int kt = 0; kt < 1024; kt += 64) {
    glds128(A + (size_t)brow * 1024 + kt, 1024, lA, t);
    glds128(Bt + (size_t)bcol * 1024 + kt, 1024, lB, t);
    __syncthreads();
#pragma unroll
    for (int ks = 0; ks < 2; ++ks) {
      const u16* pa = ks ? pA1 : pA0;
      const u16* pb = ks ? pB1 : pB0;
      bf16x8 fa[4], fb[4];
#pragma unroll
      for (int i2 = 0; i2 < 4; ++i2) {
        fa[i2] = *(const bf16x8*)(pa + i2 * 1024);
        fb[i2] = *(const bf16x8*)(pb + i2 * 1024);
      }
#pragma unroll
      for (int mi = 0; mi < 4; ++mi)
#pragma unroll
        for (int ni = 0; ni < 4; ++ni)
          acc[mi][ni] = __builtin_amdgcn_mfma_f32_16x16x32_bf16(
              fa[mi], fb[ni], acc[mi][ni], 0, 0, 0);
    }
    __syncthreads();
  }
  int wrb = (wid >> 1) * 64, wcb = (wid & 1) * 64;
  int rj = g * 4, cj = c15;
#pragma unroll
  for (int mi = 0; mi < 4; ++mi)
#pragma unroll
    for (int ni = 0; ni < 4; ++ni)
#pragma unroll
      for (int j = 0; j < 4; ++j)
        C[(size_t)(brow + wrb + mi * 16 + rj + j) * 1024 +
          (bcol + wcb + ni * 16 + cj)] = f2bf(acc[mi][ni][j] * scale);
}

// ---------------- attention pass 1: 32 q-rows per wave (LDS-traffic halved) --
// 128 threads = 2 waves; wave w owns rows [w*32, w*32+32) of the 64-row strip.
// Each K/V fragment read now feeds 2x the MFMA work (16 K + 16 V reads -> 96
// MFMAs vs 34 reads -> 48 before). p1 was LDS-read-throughput bound.
__global__ __launch_bounds__(128) void fused_p1(
    const u16* __restrict__ Cq, const u16* __restrict__ Ck,
    const u16* __restrict__ vt, const u64* __restrict__ mb,
    float* __restrict__ invbuf, u16* __restrict__ Ao) {
  __shared__ u16 lKr[64 * 64], lKi[64 * 64], lV[128 * 64], lP[64 * 64];
  int t = threadIdx.x, lane = t & 63, w = t >> 6;  // w in 0..1
  int c15 = lane & 15, g = lane >> 4, l7 = lane & 7;
  int f = blockIdx.x + (int)gridDim.x * blockIdx.y;  // 0..511
  int wk = (f & 7) * 64 + (f >> 3);                  // bijective XCD chunking
  int strip = wk & 31, z = wk >> 5;
  int b = z >> 3, h = z & 7;
  int q0 = strip * 64;
  int arow = w * 32 + c15;        // first A-row; second is arow+16
  int rbase = w * 32 + (g << 2);  // first acc-row base; second is +16

  bf16x8 q0r[2], q1r[2], q0i[2], q1i[2], nq0r[2], nq1r[2];
#pragma unroll
  for (int rq = 0; rq < 2; ++rq) {
    const u16* Qrow =
        Cq + ((size_t)(b * 2048 + q0 + arow + rq * 16)) * 1024 + h * 64;
    q0r[rq] = *(const bf16x8*)(Qrow + g * 8);
    q1r[rq] = *(const bf16x8*)(Qrow + 32 + g * 8);
    q0i[rq] = *(const bf16x8*)(Qrow + 512 + g * 8);
    q1i[rq] = *(const bf16x8*)(Qrow + 544 + g * 8);
    nq0r[rq] = negv(q0r[rq]);
    nq1r[rq] = negv(q1r[rq]);
  }

  int sw0 = ((g ^ l7) << 3), sw1 = (((4 | g) ^ l7) << 3);
  const u16 *pKr0 = lKr + c15 * 64 + sw0, *pKr1 = lKr + c15 * 64 + sw1;
  const u16 *pKi0 = lKi + c15 * 64 + sw0, *pKi1 = lKi + c15 * 64 + sw1;
  const u16 *pV0 = lV + c15 * 64 + sw0, *pV1 = lV + c15 * 64 + sw1;
  const u16 *pPa0 = lP + arow * 64 + sw0, *pPa1 = lP + arow * 64 + sw1;
  const u16 *pPb0 = lP + (arow + 16) * 64 + sw0;
  const u16 *pPb1 = lP + (arow + 16) * 64 + sw1;

  size_t mbase = ((size_t)(b * 2048 + q0 + rbase)) * 32;  // rq*16*32 extra
  float s[2][4] = {{0.f, 0.f, 0.f, 0.f}, {0.f, 0.f, 0.f, 0.f}};
  f32x4 zero = {0.f, 0.f, 0.f, 0.f};
  f32x4 o[2][8];
#pragma unroll
  for (int rq = 0; rq < 2; ++rq)
#pragma unroll
    for (int ni = 0; ni < 8; ++ni) o[rq][ni] = zero;

  const u16* Kb = Ck + ((size_t)(b * 2048)) * 1024 + h * 64;
  const u16* Vb = vt + (size_t)z * 262144;

  for (int tl = 0; tl < 32; ++tl) {
    int l0 = tl * 64;
    if (tl) __syncthreads();
    glds64h(Kb + (size_t)l0 * 1024, 1024, lKr, t);
    glds64h(Kb + (size_t)l0 * 1024 + 512, 1024, lKi, t);
    glds128h(Vb + l0, 2048, lV, t);
    __syncthreads();
    f32x4 sr[2][4], si[2][4];
#pragma unroll
    for (int rq = 0; rq < 2; ++rq)
#pragma unroll
      for (int ni = 0; ni < 4; ++ni) { sr[rq][ni] = zero; si[rq][ni] = zero; }
#pragma unroll
    for (int ni = 0; ni < 4; ++ni) {
      bf16x8 g0 = *(const bf16x8*)(pKr0 + ni * 1024);
      bf16x8 g1 = *(const bf16x8*)(pKi0 + ni * 1024);
      bf16x8 h0 = *(const bf16x8*)(pKr1 + ni * 1024);
      bf16x8 h1 = *(const bf16x8*)(pKi1 + ni * 1024);
#pragma unroll
      for (int rq = 0; rq < 2; ++rq) {
        sr[rq][ni] = __builtin_amdgcn_mfma_f32_16x16x32_bf16(q0r[rq], g0, sr[rq][ni], 0, 0, 0);
        sr[rq][ni] = __builtin_amdgcn_mfma_f32_16x16x32_bf16(q0i[rq], g1, sr[rq][ni], 0, 0, 0);
        si[rq][ni] = __builtin_amdgcn_mfma_f32_16x16x32_bf16(q0i[rq], g0, si[rq][ni], 0, 0, 0);
        si[rq][ni] = __builtin_amdgcn_mfma_f32_16x16x32_bf16(nq0r[rq], g1, si[rq][ni], 0, 0, 0);
        sr[rq][ni] = __builtin_amdgcn_mfma_f32_16x16x32_bf16(q1r[rq], h0, sr[rq][ni], 0, 0, 0);
        sr[rq][ni] = __builtin_amdgcn_mfma_f32_16x16x32_bf16(q1i[rq], h1, sr[rq][ni], 0, 0, 0);
        si[rq][ni] = __builtin_amdgcn_mfma_f32_16x16x32_bf16(q1i[rq], h0, si[rq][ni], 0, 0, 0);
        si[rq][ni] = __builtin_amdgcn_mfma_f32_16x16x32_bf16(nq1r[rq], h1, si[rq][ni], 0, 0, 0);
      }
    }
#pragma unroll
    for (int rq = 0; rq < 2; ++rq) {
      u64 wm[4];
#pragma unroll
      for (int j = 0; j < 4; ++j)
        wm[j] = mb[mbase + (size_t)rq * 512 + (size_t)j * 32 + tl];
#pragma unroll
      for (int ni = 0; ni < 4; ++ni) {
        int cbit = ni * 16 + c15;
        int pchi = ni * 2 + (c15 >> 3);
#pragma unroll
        for (int j = 0; j < 4; ++j) {
          float n = sr[rq][ni][j] * sr[rq][ni][j] + si[rq][ni][j] * si[rq][ni][j];
          float p = __expf(__builtin_amdgcn_sqrtf(n));
          p = ((wm[j] >> cbit) & 1ull) ? p : 0.0f;
          s[rq][j] += p;
          lP[(rbase + rq * 16 + j) * 64 +
             ((pchi ^ (((g & 1) << 2) + j)) << 3) + l7] = f2bf(p);
        }
      }
    }
    {
      bf16x8 fa0a = *(const bf16x8*)pPa0;
      bf16x8 fa1a = *(const bf16x8*)pPa1;
      bf16x8 fa0b = *(const bf16x8*)pPb0;
      bf16x8 fa1b = *(const bf16x8*)pPb1;
#pragma unroll
      for (int ni = 0; ni < 8; ++ni) {
        bf16x8 fb0 = *(const bf16x8*)(pV0 + ni * 1024);
        bf16x8 fb1 = *(const bf16x8*)(pV1 + ni * 1024);
        o[0][ni] = __builtin_amdgcn_mfma_f32_16x16x32_bf16(fa0a, fb0, o[0][ni], 0, 0, 0);
        o[0][ni] = __builtin_amdgcn_mfma_f32_16x16x32_bf16(fa1a, fb1, o[0][ni], 0, 0, 0);
        o[1][ni] = __builtin_amdgcn_mfma_f32_16x16x32_bf16(fa0b, fb0, o[1][ni], 0, 0, 0);
        o[1][ni] = __builtin_amdgcn_mfma_f32_16x16x32_bf16(fa1b, fb1, o[1][ni], 0, 0, 0);
      }
    }
  }
#pragma unroll
  for (int rq = 0; rq < 2; ++rq) {
    float inv[4];
#pragma unroll
    for (int j = 0; j < 4; ++j) {
      float sj = s[rq][j];
#pragma unroll
      for (int off = 1; off < 16; off <<= 1) sj += __shfl_xor(sj, off);
      inv[j] = 1.0f / sj;
    }
    if (c15 == 0) {
#pragma unroll
      for (int j = 0; j < 4; ++j)
        invbuf[z * 2048 + q0 + rbase + rq * 16 + j] = inv[j];
    }
#pragma unroll
    for (int ni = 0; ni < 8; ++ni) {
      int c = ni * 16 + c15;
      int nout = (c < 64) ? (h * 64 + c) : (512 + h * 64 + (c - 64));
#pragma unroll
      for (int j = 0; j < 4; ++j)
        Ao[((size_t)(b * 2048 + q0 + rbase + rq * 16 + j)) * 1024 + nout] =
            f2bf(o[rq][ni][j] * inv[j]);
    }
  }
}

// ---------------- attention pass 2: 32 q-rows per wave ----------------------
__global__ __launch_bounds__(128) void attn_p2(
    const u16* __restrict__ Cq, const u16* __restrict__ Ck,
    const u64* __restrict__ mb, const float* __restrict__ invbuf,
    float* __restrict__ attn) {
  __shared__ u16 lKr[64 * 64], lKi[64 * 64];
  int t = threadIdx.x, lane = t & 63, w = t >> 6;  // w in 0..1
  int c15 = lane & 15, g = lane >> 4, l7 = lane & 7;
  int f = blockIdx.x + (int)gridDim.x * blockIdx.y;  // 0..2047
  int wk = (f & 7) * 256 + (f >> 3);                 // bijective XCD chunking
  int z = wk >> 7;
  int rem = wk & 127;
  int strip = rem >> 2, kc = rem & 3;
  int b = z >> 3, h = z & 7;
  int q0 = strip * 64;
  int arow = w * 32 + c15;
  int rbase = w * 32 + (g << 2);

  bf16x8 q0r[2], q1r[2], q0i[2], q1i[2], nq0r[2], nq1r[2];
#pragma unroll
  for (int rq = 0; rq < 2; ++rq) {
    const u16* Qrow =
        Cq + ((size_t)(b * 2048 + q0 + arow + rq * 16)) * 1024 + h * 64;
    q0r[rq] = *(const bf16x8*)(Qrow + g * 8);
    q1r[rq] = *(const bf16x8*)(Qrow + 32 + g * 8);
    q0i[rq] = *(const bf16x8*)(Qrow + 512 + g * 8);
    q1i[rq] = *(const bf16x8*)(Qrow + 544 + g * 8);
    nq0r[rq] = negv(q0r[rq]);
    nq1r[rq] = negv(q1r[rq]);
  }

  int sw0 = ((g ^ l7) << 3), sw1 = (((4 | g) ^ l7) << 3);
  const u16 *pKr0 = lKr + c15 * 64 + sw0, *pKr1 = lKr + c15 * 64 + sw1;
  const u16 *pKi0 = lKi + c15 * 64 + sw0, *pKi1 = lKi + c15 * 64 + sw1;

  size_t mbase = ((size_t)(b * 2048 + q0 + rbase)) * 32;
  float inv[2][4];
#pragma unroll
  for (int rq = 0; rq < 2; ++rq)
#pragma unroll
    for (int j = 0; j < 4; ++j)
      inv[rq][j] = invbuf[z * 2048 + q0 + rbase + rq * 16 + j];
  f32x4 zero = {0.f, 0.f, 0.f, 0.f};
  const u16* Kb = Ck + ((size_t)(b * 2048)) * 1024 + h * 64;
  float* out0 = attn + ((size_t)z * 2048 + q0 + rbase) * 2048 + c15;
  float* out1 = out0 + (size_t)16 * 2048;

  for (int tt2 = 0; tt2 < 8; ++tt2) {
    int tl = kc * 8 + tt2;
    int l0 = tl * 64;
    if (tt2) __syncthreads();
    glds64h(Kb + (size_t)l0 * 1024, 1024, lKr, t);
    glds64h(Kb + (size_t)l0 * 1024 + 512, 1024, lKi, t);
    __syncthreads();
    f32x4 sr[2][4], si[2][4];
#pragma unroll
    for (int rq = 0; rq < 2; ++rq)
#pragma unroll
      for (int ni = 0; ni < 4; ++ni) { sr[rq][ni] = zero; si[rq][ni] = zero; }
#pragma unroll
    for (int ni = 0; ni < 4; ++ni) {
      bf16x8 g0 = *(const bf16x8*)(pKr0 + ni * 1024);
      bf16x8 g1 = *(const bf16x8*)(pKi0 + ni * 1024);
      bf16x8 h0 = *(const bf16x8*)(pKr1 + ni * 1024);
      bf16x8 h1 = *(const bf16x8*)(pKi1 + ni * 1024);
#pragma unroll
      for (int rq = 0; rq < 2; ++rq) {
        sr[rq][ni] = __builtin_amdgcn_mfma_f32_16x16x32_bf16(q0r[rq], g0, sr[rq][ni], 0, 0, 0);
        sr[rq][ni] = __builtin_amdgcn_mfma_f32_16x16x32_bf16(q0i[rq], g1, sr[rq][ni], 0, 0, 0);
        si[rq][ni] = __builtin_amdgcn_mfma_f32_16x16x32_bf16(q0i[rq], g0, si[rq][ni], 0, 0, 0);
        si[rq][ni] = __builtin_amdgcn_mfma_f32_16x16x32_bf16(nq0r[rq], g1, si[rq][ni], 0, 0, 0);
        sr[rq][ni] = __builtin_amdgcn_mfma_f32_16x16x32_bf16(q1r[rq], h0, sr[rq][ni], 0, 0, 0);
        sr[rq][ni] = __builtin_amdgcn_mfma_f32_16x16x32_bf16(q1i[rq], h1, sr[rq][ni], 0, 0, 0);
        si[rq][ni] = __builtin_amdgcn_mfma_f32_16x16x32_bf16(q1i[rq], h0, si[rq][ni], 0, 0, 0);
        si[rq][ni] = __builtin_amdgcn_mfma_f32_16x16x32_bf16(nq1r[rq], h1, si[rq][ni], 0, 0, 0);
      }
    }
#pragma unroll
    for (int rq = 0; rq < 2; ++rq) {
      u64 wm[4];
#pragma unroll
      for (int j = 0; j < 4; ++j)
        wm[j] = mb[mbase + (size_t)rq * 512 + (size_t)j * 32 + tl];
      float* outp = (rq ? out1 : out0) + l0;
#pragma unroll
      for (int ni = 0; ni < 4; ++ni) {
        int cbit = ni * 16 + c15;
#pragma unroll
        for (int j = 0; j < 4; ++j) {
          float n = sr[rq][ni][j] * sr[rq][ni][j] + si[rq][ni][j] * si[rq][ni][j];
          float p = __expf(__builtin_amdgcn_sqrtf(n)) * inv[rq][j];
          p = ((wm[j] >> cbit) & 1ull) ? p : 0.0f;
          outp[(size_t)j * 2048 + ni * 16] = p;
        }
      }
    }
  }
}

// ---------------- out-proj + residual -> y (f32, in d_out) ----------------
__global__ __launch_bounds__(256) void gemm_oproj(
    const u16* __restrict__ A, const u16* __restrict__ Bt,
    const float* __restrict__ resR, const float* __restrict__ resI,
    float* __restrict__ outR, float* __restrict__ outI) {
  __shared__ u16 lA[128 * 64], lB[128 * 64];
  int t = threadIdx.x, lane = t & 63, wid = t >> 6;
  int c15 = lane & 15, g = lane >> 4, l7 = lane & 7;
  int brow = blockIdx.y * 128, bcol = blockIdx.x * 128;
  int sw0 = ((g ^ l7) << 3), sw1 = (((4 | g) ^ l7) << 3);
  int wr0 = (wid >> 1) * 64 + c15, wc0 = (wid & 1) * 64 + c15;
  const u16 *pA0 = lA + wr0 * 64 + sw0, *pA1 = lA + wr0 * 64 + sw1;
  const u16 *pB0 = lB + wc0 * 64 + sw0, *pB1 = lB + wc0 * 64 + sw1;
  f32x4 zero = {0.f, 0.f, 0.f, 0.f};
  f32x4 acc[4][4];
#pragma unroll
  for (int mi = 0; mi < 4; ++mi)
#pragma unroll
    for (int ni = 0; ni < 4; ++ni) acc[mi][ni] = zero;
  for (int kt = 0; kt < 1024; kt += 64) {
    glds128(A + (size_t)brow * 1024 + kt, 1024, lA, t);
    glds128(Bt + (size_t)bcol * 1024 + kt, 1024, lB, t);
    __syncthreads();
#pragma unroll
    for (int ks = 0; ks < 2; ++ks) {
      const u16* pa = ks ? pA1 : pA0;
      const u16* pb = ks ? pB1 : pB0;
      bf16x8 fa[4], fb[4];
#pragma unroll
      for (int i2 = 0; i2 < 4; ++i2) {
        fa[i2] = *(const bf16x8*)(pa + i2 * 1024);
        fb[i2] = *(const bf16x8*)(pb + i2 * 1024);
      }
#pragma unroll
      for (int mi = 0; mi < 4; ++mi)
#pragma unroll
        for (int ni = 0; ni < 4; ++ni)
          acc[mi][ni] = __builtin_amdgcn_mfma_f32_16x16x32_bf16(
              fa[mi], fb[ni], acc[mi][ni], 0, 0, 0);
    }
    __syncthreads();
  }
  int wrb = (wid >> 1) * 64, wcb = (wid & 1) * 64;
  int rj = g * 4, cj = c15;
#pragma unroll
  for (int mi = 0; mi < 4; ++mi)
#pragma unroll
    for (int ni = 0; ni < 4; ++ni)
#pragma unroll
      for (int j = 0; j < 4; ++j) {
        int row = brow + wrb + mi * 16 + rj + j;
        int col = bcol + wcb + ni * 16 + cj;
        float v = acc[mi][ni][j];
        if (col < 512)
          outR[(size_t)row * 512 + col] = v + resR[(size_t)row * 512 + col];
        else {
          int c2 = col - 512;
          outI[(size_t)row * 512 + c2] = v + resI[(size_t)row * 512 + c2];
        }
      }
}

// ---------------- complex layernorm ----------------
__global__ __launch_bounds__(256) void ln_reduce(const float* __restrict__ outR,
                                                 const float* __restrict__ outI,
                                                 float* __restrict__ stats) {
  int b = blockIdx.y;
  int t = threadIdx.x;
  size_t base = (size_t)b * 1048576 + (size_t)blockIdx.x * 2048;
  float s0 = 0.f, s1 = 0.f, s2 = 0.f, s3 = 0.f, s4 = 0.f;
#pragma unroll
  for (int p = 0; p < 8; ++p) {
    size_t e = base + p * 256 + t;
    float r = outR[e], i = outI[e];
    s0 += r; s1 += i; s2 += r * r; s3 += i * i; s4 += r * i;
  }
#pragma unroll
  for (int off = 32; off; off >>= 1) {
    s0 += __shfl_xor(s0, off); s1 += __shfl_xor(s1, off);
    s2 += __shfl_xor(s2, off); s3 += __shfl_xor(s3, off);
    s4 += __shfl_xor(s4, off);
  }
  __shared__ float red[4][5];
  if ((t & 63) == 0) {
    int w = t >> 6;
    red[w][0] = s0; red[w][1] = s1; red[w][2] = s2; red[w][3] = s3; red[w][4] = s4;
  }
  __syncthreads();
  if (t == 0) {
    float a0 = red[0][0] + red[1][0] + red[2][0] + red[3][0];
    float a1 = red[0][1] + red[1][1] + red[2][1] + red[3][1];
    float a2 = red[0][2] + red[1][2] + red[2][2] + red[3][2];
    float a3 = red[0][3] + red[1][3] + red[2][3] + red[3][3];
    float a4 = red[0][4] + red[1][4] + red[2][4] + red[3][4];
    atomicAdd(&stats[b * 8 + 0], a0);
    atomicAdd(&stats[b * 8 + 1], a1);
    atomicAdd(&stats[b * 8 + 2], a2);
    atomicAdd(&stats[b * 8 + 3], a3);
    atomicAdd(&stats[b * 8 + 4], a4);
  }
}

__global__ __launch_bounds__(256) void ln_apply(
    float* __restrict__ outR, float* __restrict__ outI,
    const float* __restrict__ stats,
    const float* __restrict__ lnwr, const float* __restrict__ lnwi,
    const float* __restrict__ lnbr, const float* __restrict__ lnbi) {
  int b = blockIdx.y;
  const float* st = stats + b * 8;
  float iN = 1.0f / 1048576.0f;
  float mr = st[0] * iN, mi = st[1] * iN;
  float Crr = st[2] * iN - mr * mr + 1e-6f;
  float Cii = st[3] * iN - mi * mi + 1e-6f;
  float Cri = st[4] * iN - mr * mi;
  float s = sqrtf(fmaxf(Crr * Cii - Cri * Cri, 0.f));
  float tt = sqrtf(Crr + Cii + 2.f * s);
  float inv = 1.0f / (s * tt);
  float Rrr = (Cii + s) * inv, Rii = (Crr + s) * inv, Rri = -Cri * inv;
  size_t e = ((size_t)blockIdx.x * 256 + threadIdx.x) * 4;
  size_t idx = (size_t)b * 1048576 + e;
  int d = (int)(e & 511);
  float4 r4 = *(float4*)(outR + idx);
  float4 i4 = *(float4*)(outI + idx);
  float4 wr = *(const float4*)(lnwr + d);
  float4 wi = *(const float4*)(lnwi + d);
  float4 br = *(const float4*)(lnbr + d);
  float4 bi = *(const float4*)(lnbi + d);
  float4 orr, oii;
#pragma unroll
  for (int j = 0; j < 4; ++j) {
    float r = ((&r4.x)[j]) - mr;
    float i = ((&i4.x)[j]) - mi;
    float nr = Rrr * r + Rri * i;
    float ni = Rii * i + Rri * r;
    (&orr.x)[j] = nr * (&wr.x)[j] - ni * (&wi.x)[j] + (&br.x)[j];
    (&oii.x)[j] = nr * (&wi.x)[j] + ni * (&wr.x)[j] + (&bi.x)[j];
  }
  *(float4*)(outR + idx) = orr;
  *(float4*)(outI + idx) = oii;
}

// ---------------- orchestration ----------------
extern "C" void kernel_launch(void* const* d_in, const int* in_sizes, int n_in,
                              void* d_out, int out_size, void* d_ws, size_t ws_size,
                              hipStream_t stream) {
  const float* q_r = (const float*)d_in[0];
  const float* q_i = (const float*)d_in[1];
  const float* k_r = (const float*)d_in[2];
  const float* k_i = (const float*)d_in[3];
  const float* v_r = (const float*)d_in[4];
  const float* v_i = (const float*)d_in[5];
  const float* wq_r = (const float*)d_in[6];
  const float* wq_i = (const float*)d_in[7];
  const float* wk_r = (const float*)d_in[8];
  const float* wk_i = (const float*)d_in[9];
  const float* wv_r = (const float*)d_in[10];
  const float* wv_i = (const float*)d_in[11];
  const float* wo_r = (const float*)d_in[12];
  const float* wo_i = (const float*)d_in[13];
  const float* ln_wr = (const float*)d_in[14];
  const float* ln_wi = (const float*)d_in[15];
  const float* ln_br = (const float*)d_in[16];
  const float* ln_bi = (const float*)d_in[17];
  const int* mask = (const int*)d_in[18];

  float* outR = (float*)d_out;
  float* outI = outR + 2097152;
  float* attn = outR + 4194304;  // final attn output (written once)

  char* ws = (char*)d_ws;
  u16* Aq = (u16*)ws;                    // 3 x 4194304 elems (packed A)
  u16* Bt = (u16*)(ws + 25165824);       // 4 x 1048576 elems (packed Bt)
  u16* Cq = (u16*)(ws + 33554432);       // 3 x 4194304 elems (proj out)
  u16* Ck = Cq + 4194304;
  u16* Cv = Cq + 8388608;
  u16* vt = Aq;                          // reuse A region after gemm_proj
  u16* Ao = (u16*)(ws + 58720256);       // 4194304 elems
  u64* mb = (u64*)(ws + 67108864);       // 131072 u64 (mask bits)
  float* stats = (float*)(ws + 69206016);
  float* invbuf = (float*)(ws + 69207040);  // 32768 floats

  prep<<<dim3(32768 + 6144 + 1024 + 1), 256, 0, stream>>>(
      q_r, q_i, k_r, k_i, v_r, v_i, wq_r, wq_i, wk_r, wk_i, wv_r, wv_i,
      wo_r, wo_i, mask, Aq, Bt, mb, stats);
  gemm_proj<<<dim3(8, 32, 3), 256, 0, stream>>>(Aq, Bt, Cq);
  pack_vt<<<dim3(64, 16), 256, 0, stream>>>(Cv, vt);
  fused_p1<<<dim3(32, 16), 128, 0, stream>>>(Cq, Ck, vt, mb, invbuf, Ao);
  attn_p2<<<dim3(128, 16), 128, 0, stream>>>(Cq, Ck, mb, invbuf, attn);
  gemm_oproj<<<dim3(8, 32), 256, 0, stream>>>(Ao, Bt + 3145728, q_r, q_i, outR, outI);
  ln_reduce<<<dim3(512, 2), 256, 0, stream>>>(outR, outI, stats);
  ln_apply<<<dim3(1024, 2), 256, 0, stream>>>(outR, outI, stats, ln_wr, ln_wi,
                                              ln_br, ln_bi);
}

// Round 14
// 337.262 us; speedup vs baseline: 1.0653x; 1.0653x over previous
//
#include <hip/hip_runtime.h>

typedef unsigned short u16;
typedef unsigned int u32;
typedef unsigned long long u64;

// B=2, L=2048, D=512, H=8, DK=DV=64, M=B*L=4096
// All GEMMs: C[M,N] = A[M,K] @ Bt[N,K]^T, bf16 inputs, f32 MFMA accum.

typedef __attribute__((ext_vector_type(8))) short bf16x8;
typedef __attribute__((ext_vector_type(4))) float f32x4;
typedef __attribute__((ext_vector_type(4))) u32 u32x4;

__device__ __forceinline__ u16 f2bf(float f) {
  u32 x = __float_as_uint(f);
  return (u16)((x + 0x7FFFu + ((x >> 16) & 1u)) >> 16);  // RNE
}
__device__ __forceinline__ u32 pk2(float a, float b) {
  return (u32)f2bf(a) | ((u32)f2bf(b) << 16);
}
__device__ __forceinline__ bf16x8 negv(bf16x8 v) {
  u32x4 x = __builtin_bit_cast(u32x4, v);
  x ^= 0x80008000u;
  return __builtin_bit_cast(bf16x8, x);
}

// ---------------- prep: pack_mask + pack_a3 + pack_bt + zero_stats ----------
__global__ __launch_bounds__(256) void prep(
    const float* __restrict__ qr, const float* __restrict__ qi,
    const float* __restrict__ kr, const float* __restrict__ ki,
    const float* __restrict__ vr, const float* __restrict__ vi,
    const float* __restrict__ wqr, const float* __restrict__ wqi,
    const float* __restrict__ wkr, const float* __restrict__ wki,
    const float* __restrict__ wvr, const float* __restrict__ wvi,
    const float* __restrict__ wor, const float* __restrict__ woi,
    const int* __restrict__ mask,
    u16* __restrict__ A, u16* __restrict__ Btb, u64* __restrict__ mb,
    float* __restrict__ stats) {
  __shared__ float tile[64][65];
  int bid = blockIdx.x;
  int t = threadIdx.x;
  if (bid < 32768) {  // ---- pack_mask ----
    int tid = bid * 256 + t;
    u64 bal = __ballot(mask[tid] != 0);
    if ((t & 63) == 0) mb[tid >> 6] = bal;
    return;
  }
  bid -= 32768;
  if (bid < 6144) {  // ---- pack_a3: Aq/Ak/Av [4096][1024] = [xr|xi] ----
    int z = bid >> 11;
    int bx = bid & 2047;
    const float* r  = (z == 0) ? qr : (z == 1) ? kr : vr;
    const float* im = (z == 0) ? qi : (z == 1) ? ki : vi;
    int c = bx * 256 + t;
    int m = c >> 7;
    int ck = (c & 127) * 8;
    const float* s = (ck < 512) ? (r + (size_t)m * 512 + ck)
                                : (im + (size_t)m * 512 + (ck - 512));
    float4 a = ((const float4*)s)[0];
    float4 b = ((const float4*)s)[1];
    uint4 o;
    o.x = pk2(a.x, a.y); o.y = pk2(a.z, a.w);
    o.z = pk2(b.x, b.y); o.w = pk2(b.z, b.w);
    ((uint4*)(A + (size_t)z * 4194304))[c] = o;
    return;
  }
  bid -= 6144;
  if (bid < 1024) {  // ---- pack_bt: Bt[z] [1024 n][1024 k] ----
    int z = bid >> 8;
    int bx = bid & 255;
    const float* wr = (z==0)?wqr:(z==1)?wkr:(z==2)?wvr:wor;
    const float* wi = (z==0)?wqi:(z==1)?wki:(z==2)?wvi:woi;
    u16* Bt = Btb + (size_t)z * 1048576;
    int n0 = (bx >> 4) * 64;
    int k0 = (bx & 15) * 64;
    bool nlow = (n0 < 512), klow = (k0 < 512);
    const float* src = nlow ? (klow ? wr : wi) : (klow ? wi : wr);
    float sgn = (nlow && !klow) ? -1.0f : 1.0f;
    int col0 = nlow ? n0 : n0 - 512;
    int kr0 = klow ? k0 : k0 - 512;
    {
      int rr = t >> 2, cc = (t & 3) * 16;
      const float4* s = (const float4*)(src + (size_t)(kr0 + rr) * 512 + col0 + cc);
#pragma unroll
      for (int j = 0; j < 4; ++j) {
        float4 v = s[j];
        tile[rr][cc + j*4 + 0] = v.x; tile[rr][cc + j*4 + 1] = v.y;
        tile[rr][cc + j*4 + 2] = v.z; tile[rr][cc + j*4 + 3] = v.w;
      }
    }
    __syncthreads();
    {
      int nn = t >> 2, kc = (t & 3) * 16;
      u32 w[8];
#pragma unroll
      for (int j = 0; j < 8; ++j)
        w[j] = pk2(sgn * tile[kc + 2*j][nn], sgn * tile[kc + 2*j + 1][nn]);
      uint4* d = (uint4*)(Bt + (size_t)(n0 + nn) * 1024 + k0 + kc);
      d[0] = make_uint4(w[0], w[1], w[2], w[3]);
      d[1] = make_uint4(w[4], w[5], w[6], w[7]);
    }
    return;
  }
  if (t < 16) stats[t] = 0.0f;
}

// vt [16][128 c][2048 l] bf16 : transposed V (c<64 real, c>=64 imag)
__global__ __launch_bounds__(256) void pack_vt(const u16* __restrict__ Cvm,
                                               u16* __restrict__ vt) {
  int z = blockIdx.y;
  int b = z >> 3, h = z & 7;
  int lt = blockIdx.x >> 1, ct = blockIdx.x & 1;
  int l0 = lt * 64, c0 = ct * 64;
  int n0 = (ct == 0) ? (h * 64) : (512 + h * 64);
  __shared__ u16 tile[64][80];
  int t = threadIdx.x;
  {
    int lr = t >> 2, cc = (t & 3) * 16;
    const uint4* s = (const uint4*)(Cvm + ((size_t)(b * 2048 + l0 + lr)) * 1024 + n0 + cc);
    uint4 v0 = s[0], v1 = s[1];
    *(uint4*)&tile[lr][cc] = v0;
    *(uint4*)&tile[lr][cc + 8] = v1;
  }
  __syncthreads();
  {
    int cr = t >> 2, lc = (t & 3) * 16;
    u32 w[8];
#pragma unroll
    for (int j = 0; j < 8; ++j)
      w[j] = (u32)tile[lc + 2*j][cr] | ((u32)tile[lc + 2*j + 1][cr] << 16);
    uint4* d = (uint4*)(vt + ((size_t)z * 128 + c0 + cr) * 2048 + l0 + lc);
    d[0] = make_uint4(w[0], w[1], w[2], w[3]);
    d[1] = make_uint4(w[4], w[5], w[6], w[7]);
  }
}

// ---------------- async staging via global_load_lds (width 16) ----------------
// XOR-swizzled LDS layout (chunk c of row r at r*64+((c^(r&7))<<3)), built per
// guide rule #21: LINEAR LDS dest (wave base + lane*16B), PRE-SWIZZLED global
// source col = (lane&7) ^ (lane>>3). Fragment reads unchanged.
__device__ __forceinline__ void glds128(const u16* __restrict__ g, int ld,
                                        u16* lds, int t) {
  int lane = t & 63, w = t >> 6;
  int sub = lane >> 3;
  int cs = (lane & 7) ^ sub;
#pragma unroll
  for (int p = 0; p < 4; ++p) {
    int r = p * 32 + w * 8 + sub;
    const u16* ga = g + (size_t)r * ld + cs * 8;
    u16* la = lds + (size_t)(p * 32 + w * 8) * 64;  // wave-uniform base
    __builtin_amdgcn_global_load_lds(
        (const __attribute__((address_space(1))) void*)ga,
        (__attribute__((address_space(3))) void*)la, 16, 0, 0);
  }
}
__device__ __forceinline__ void glds64(const u16* __restrict__ g, int ld,
                                       u16* lds, int t) {
  int lane = t & 63, w = t >> 6;
  int sub = lane >> 3;
  int cs = (lane & 7) ^ sub;
#pragma unroll
  for (int p = 0; p < 2; ++p) {
    int r = p * 32 + w * 8 + sub;
    const u16* ga = g + (size_t)r * ld + cs * 8;
    u16* la = lds + (size_t)(p * 32 + w * 8) * 64;
    __builtin_amdgcn_global_load_lds(
        (const __attribute__((address_space(1))) void*)ga,
        (__attribute__((address_space(3))) void*)la, 16, 0, 0);
  }
}

// ---------------- projection GEMM: C[4096,1024] bf16 = A @ Bt^T (x3 via z) ----------------
__global__ __launch_bounds__(256) void gemm_proj(const u16* __restrict__ Abase,
                                                 const u16* __restrict__ Btbase,
                                                 u16* __restrict__ Cbase) {
  __shared__ u16 lA[128 * 64], lB[128 * 64];
  int t = threadIdx.x, lane = t & 63, wid = t >> 6;
  int c15 = lane & 15, g = lane >> 4, l7 = lane & 7;
  int z = blockIdx.z;
  const u16* A  = Abase  + (size_t)z * 4194304;
  const u16* Bt = Btbase + (size_t)z * 1048576;
  u16* C = Cbase + (size_t)z * 4194304;
  int brow = blockIdx.y * 128, bcol = blockIdx.x * 128;
  float scale = (z == 0) ? 0.125f : 1.0f;  // q / sqrt(DK)
  int sw0 = ((g ^ l7) << 3), sw1 = (((4 | g) ^ l7) << 3);
  int wr0 = (wid >> 1) * 64 + c15, wc0 = (wid & 1) * 64 + c15;
  const u16 *pA0 = lA + wr0 * 64 + sw0, *pA1 = lA + wr0 * 64 + sw1;
  const u16 *pB0 = lB + wc0 * 64 + sw0, *pB1 = lB + wc0 * 64 + sw1;
  f32x4 zero = {0.f, 0.f, 0.f, 0.f};
  f32x4 acc[4][4];
#pragma unroll
  for (int mi = 0; mi < 4; ++mi)
#pragma unroll
    for (int ni = 0; ni < 4; ++ni) acc[mi][ni] = zero;
  for (int kt = 0; kt < 1024; kt += 64) {
    glds128(A + (size_t)brow * 1024 + kt, 1024, lA, t);
    glds128(Bt + (size_t)bcol * 1024 + kt, 1024, lB, t);
    __syncthreads();
#pragma unroll
    for (int ks = 0; ks < 2; ++ks) {
      const u16* pa = ks ? pA1 : pA0;
      const u16* pb = ks ? pB1 : pB0;
      bf16x8 fa[4], fb[4];
#pragma unroll
      for (int i2 = 0; i2 < 4; ++i2) {
        fa[i2] = *(const bf16x8*)(pa + i2 * 1024);
        fb[i2] = *(const bf16x8*)(pb + i2 * 1024);
      }
#pragma unroll
      for (int mi = 0; mi < 4; ++mi)
#pragma unroll
        for (int ni = 0; ni < 4; ++ni)
          acc[mi][ni] = __builtin_amdgcn_mfma_f32_16x16x32_bf16(
              fa[mi], fb[ni], acc[mi][ni], 0, 0, 0);
    }
    __syncthreads();
  }
  int wrb = (wid >> 1) * 64, wcb = (wid & 1) * 64;
  int rj = g * 4, cj = c15;
#pragma unroll
  for (int mi = 0; mi < 4; ++mi)
#pragma unroll
    for (int ni = 0; ni < 4; ++ni)
#pragma unroll
      for (int j = 0; j < 4; ++j)
        C[(size_t)(brow + wrb + mi * 16 + rj + j) * 1024 +
          (bcol + wcb + ni * 16 + cj)] = f2bf(acc[mi][ni][j] * scale);
}

// ---------------- attention pass 1 (R9 structure + glds staging) ----------
// Per block: 64 q-rows of one (b,h). No-max softmax (|score| bounded, exp
// safe in f32; masked -> 0). Writes Ao = (P@V)/s and invbuf = 1/s for pass 2.
__global__ __launch_bounds__(256, 3) void fused_p1(
    const u16* __restrict__ Cq, const u16* __restrict__ Ck,
    const u16* __restrict__ vt, const u64* __restrict__ mb,
    float* __restrict__ invbuf, u16* __restrict__ Ao) {
  __shared__ u16 lKr[64 * 64], lKi[64 * 64], lV[128 * 64], lP[64 * 64];
  int t = threadIdx.x, lane = t & 63, w = t >> 6;
  int c15 = lane & 15, g = lane >> 4, l7 = lane & 7;
  int f = blockIdx.x + (int)gridDim.x * blockIdx.y;  // 0..511
  int wk = (f & 7) * 64 + (f >> 3);                  // bijective XCD chunking
  int strip = wk & 31, z = wk >> 5;
  int b = z >> 3, h = z & 7;
  int q0 = strip * 64;
  int arow = w * 16 + c15;
  int rbase = w * 16 + (g << 2);

  const u16* Qrow = Cq + ((size_t)(b * 2048 + q0 + arow)) * 1024 + h * 64;
  bf16x8 q0r = *(const bf16x8*)(Qrow + g * 8);
  bf16x8 q1r = *(const bf16x8*)(Qrow + 32 + g * 8);
  bf16x8 q0i = *(const bf16x8*)(Qrow + 512 + g * 8);
  bf16x8 q1i = *(const bf16x8*)(Qrow + 544 + g * 8);
  bf16x8 nq0r = negv(q0r), nq1r = negv(q1r);

  int sw0 = ((g ^ l7) << 3), sw1 = (((4 | g) ^ l7) << 3);
  const u16 *pKr0 = lKr + c15 * 64 + sw0, *pKr1 = lKr + c15 * 64 + sw1;
  const u16 *pKi0 = lKi + c15 * 64 + sw0, *pKi1 = lKi + c15 * 64 + sw1;
  const u16 *pV0 = lV + c15 * 64 + sw0, *pV1 = lV + c15 * 64 + sw1;
  const u16 *pP0 = lP + arow * 64 + sw0, *pP1 = lP + arow * 64 + sw1;

  size_t mbase = ((size_t)(b * 2048 + q0 + rbase)) * 32;
  float s[4] = {0.f, 0.f, 0.f, 0.f};
  f32x4 zero = {0.f, 0.f, 0.f, 0.f};
  f32x4 o[8];
#pragma unroll
  for (int ni = 0; ni < 8; ++ni) o[ni] = zero;

  const u16* Kb = Ck + ((size_t)(b * 2048)) * 1024 + h * 64;
  const u16* Vb = vt + (size_t)z * 262144;

  for (int tl = 0; tl < 32; ++tl) {
    int l0 = tl * 64;
    if (tl) __syncthreads();
    glds64(Kb + (size_t)l0 * 1024, 1024, lKr, t);
    glds64(Kb + (size_t)l0 * 1024 + 512, 1024, lKi, t);
    glds128(Vb + l0, 2048, lV, t);
    __syncthreads();
    f32x4 sr[4], si[4];
#pragma unroll
    for (int ni = 0; ni < 4; ++ni) { sr[ni] = zero; si[ni] = zero; }
#pragma unroll
    for (int ni = 0; ni < 4; ++ni) {
      bf16x8 g0 = *(const bf16x8*)(pKr0 + ni * 1024);
      bf16x8 g1 = *(const bf16x8*)(pKi0 + ni * 1024);
      sr[ni] = __builtin_amdgcn_mfma_f32_16x16x32_bf16(q0r, g0, sr[ni], 0, 0, 0);
      sr[ni] = __builtin_amdgcn_mfma_f32_16x16x32_bf16(q0i, g1, sr[ni], 0, 0, 0);
      si[ni] = __builtin_amdgcn_mfma_f32_16x16x32_bf16(q0i, g0, si[ni], 0, 0, 0);
      si[ni] = __builtin_amdgcn_mfma_f32_16x16x32_bf16(nq0r, g1, si[ni], 0, 0, 0);
      bf16x8 h0 = *(const bf16x8*)(pKr1 + ni * 1024);
      bf16x8 h1 = *(const bf16x8*)(pKi1 + ni * 1024);
      sr[ni] = __builtin_amdgcn_mfma_f32_16x16x32_bf16(q1r, h0, sr[ni], 0, 0, 0);
      sr[ni] = __builtin_amdgcn_mfma_f32_16x16x32_bf16(q1i, h1, sr[ni], 0, 0, 0);
      si[ni] = __builtin_amdgcn_mfma_f32_16x16x32_bf16(q1i, h0, si[ni], 0, 0, 0);
      si[ni] = __builtin_amdgcn_mfma_f32_16x16x32_bf16(nq1r, h1, si[ni], 0, 0, 0);
    }
    u64 wm[4];
#pragma unroll
    for (int j = 0; j < 4; ++j) wm[j] = mb[mbase + (size_t)j * 32 + tl];
#pragma unroll
    for (int ni = 0; ni < 4; ++ni) {
      int cbit = ni * 16 + c15;
      int pchi = ni * 2 + (c15 >> 3);
#pragma unroll
      for (int j = 0; j < 4; ++j) {
        float n = sr[ni][j] * sr[ni][j] + si[ni][j] * si[ni][j];
        float p = __expf(__builtin_amdgcn_sqrtf(n));
        p = ((wm[j] >> cbit) & 1ull) ? p : 0.0f;
        s[j] += p;
        lP[(rbase + j) * 64 + ((pchi ^ (((g & 1) << 2) + j)) << 3) + l7] = f2bf(p);
      }
    }
    {
      bf16x8 fa0 = *(const bf16x8*)pP0;
      bf16x8 fa1 = *(const bf16x8*)pP1;
#pragma unroll
      for (int ni = 0; ni < 8; ++ni) {
        bf16x8 fb0 = *(const bf16x8*)(pV0 + ni * 1024);
        bf16x8 fb1 = *(const bf16x8*)(pV1 + ni * 1024);
        o[ni] = __builtin_amdgcn_mfma_f32_16x16x32_bf16(fa0, fb0, o[ni], 0, 0, 0);
        o[ni] = __builtin_amdgcn_mfma_f32_16x16x32_bf16(fa1, fb1, o[ni], 0, 0, 0);
      }
    }
  }
  float inv[4];
#pragma unroll
  for (int j = 0; j < 4; ++j) {
    float sj = s[j];
#pragma unroll
    for (int off = 1; off < 16; off <<= 1) sj += __shfl_xor(sj, off);
    inv[j] = 1.0f / sj;
  }
  if (c15 == 0) {
#pragma unroll
    for (int j = 0; j < 4; ++j)
      invbuf[z * 2048 + q0 + rbase + j] = inv[j];
  }
#pragma unroll
  for (int ni = 0; ni < 8; ++ni) {
    int c = ni * 16 + c15;
    int nout = (c < 64) ? (h * 64 + c) : (512 + h * 64 + (c - 64));
#pragma unroll
    for (int j = 0; j < 4; ++j)
      Ao[((size_t)(b * 2048 + q0 + rbase + j)) * 1024 + nout] =
          f2bf(o[ni][j] * inv[j]);
  }
}

// ---------------- attention pass 2: recompute scores, write attn -----------
__global__ __launch_bounds__(256, 3) void attn_p2(
    const u16* __restrict__ Cq, const u16* __restrict__ Ck,
    const u64* __restrict__ mb, const float* __restrict__ invbuf,
    float* __restrict__ attn) {
  __shared__ u16 lKr[64 * 64], lKi[64 * 64];
  int t = threadIdx.x, lane = t & 63, w = t >> 6;
  int c15 = lane & 15, g = lane >> 4, l7 = lane & 7;
  int f = blockIdx.x + (int)gridDim.x * blockIdx.y;  // 0..2047
  int wk = (f & 7) * 256 + (f >> 3);                 // bijective XCD chunking
  int z = wk >> 7;
  int rem = wk & 127;
  int strip = rem >> 2, kc = rem & 3;
  int b = z >> 3, h = z & 7;
  int q0 = strip * 64;
  int arow = w * 16 + c15;
  int rbase = w * 16 + (g << 2);

  const u16* Qrow = Cq + ((size_t)(b * 2048 + q0 + arow)) * 1024 + h * 64;
  bf16x8 q0r = *(const bf16x8*)(Qrow + g * 8);
  bf16x8 q1r = *(const bf16x8*)(Qrow + 32 + g * 8);
  bf16x8 q0i = *(const bf16x8*)(Qrow + 512 + g * 8);
  bf16x8 q1i = *(const bf16x8*)(Qrow + 544 + g * 8);
  bf16x8 nq0r = negv(q0r), nq1r = negv(q1r);

  int sw0 = ((g ^ l7) << 3), sw1 = (((4 | g) ^ l7) << 3);
  const u16 *pKr0 = lKr + c15 * 64 + sw0, *pKr1 = lKr + c15 * 64 + sw1;
  const u16 *pKi0 = lKi + c15 * 64 + sw0, *pKi1 = lKi + c15 * 64 + sw1;

  size_t mbase = ((size_t)(b * 2048 + q0 + rbase)) * 32;
  float inv[4];
#pragma unroll
  for (int j = 0; j < 4; ++j) inv[j] = invbuf[z * 2048 + q0 + rbase + j];
  f32x4 zero = {0.f, 0.f, 0.f, 0.f};
  const u16* Kb = Ck + ((size_t)(b * 2048)) * 1024 + h * 64;
  float* arow_out = attn + ((size_t)z * 2048 + q0 + rbase) * 2048 + c15;

  for (int tt2 = 0; tt2 < 8; ++tt2) {
    int tl = kc * 8 + tt2;
    int l0 = tl * 64;
    if (tt2) __syncthreads();
    glds64(Kb + (size_t)l0 * 1024, 1024, lKr, t);
    glds64(Kb + (size_t)l0 * 1024 + 512, 1024, lKi, t);
    __syncthreads();
    f32x4 sr[4], si[4];
#pragma unroll
    for (int ni = 0; ni < 4; ++ni) { sr[ni] = zero; si[ni] = zero; }
#pragma unroll
    for (int ni = 0; ni < 4; ++ni) {
      bf16x8 g0 = *(const bf16x8*)(pKr0 + ni * 1024);
      bf16x8 g1 = *(const bf16x8*)(pKi0 + ni * 1024);
      sr[ni] = __builtin_amdgcn_mfma_f32_16x16x32_bf16(q0r, g0, sr[ni], 0, 0, 0);
      sr[ni] = __builtin_amdgcn_mfma_f32_16x16x32_bf16(q0i, g1, sr[ni], 0, 0, 0);
      si[ni] = __builtin_amdgcn_mfma_f32_16x16x32_bf16(q0i, g0, si[ni], 0, 0, 0);
      si[ni] = __builtin_amdgcn_mfma_f32_16x16x32_bf16(nq0r, g1, si[ni], 0, 0, 0);
      bf16x8 h0 = *(const bf16x8*)(pKr1 + ni * 1024);
      bf16x8 h1 = *(const bf16x8*)(pKi1 + ni * 1024);
      sr[ni] = __builtin_amdgcn_mfma_f32_16x16x32_bf16(q1r, h0, sr[ni], 0, 0, 0);
      sr[ni] = __builtin_amdgcn_mfma_f32_16x16x32_bf16(q1i, h1, sr[ni], 0, 0, 0);
      si[ni] = __builtin_amdgcn_mfma_f32_16x16x32_bf16(q1i, h0, si[ni], 0, 0, 0);
      si[ni] = __builtin_amdgcn_mfma_f32_16x16x32_bf16(nq1r, h1, si[ni], 0, 0, 0);
    }
    u64 wm[4];
#pragma unroll
    for (int j = 0; j < 4; ++j) wm[j] = mb[mbase + (size_t)j * 32 + tl];
    float* outp = arow_out + l0;
#pragma unroll
    for (int ni = 0; ni < 4; ++ni) {
      int cbit = ni * 16 + c15;
#pragma unroll
      for (int j = 0; j < 4; ++j) {
        float n = sr[ni][j] * sr[ni][j] + si[ni][j] * si[ni][j];
        float p = __expf(__builtin_amdgcn_sqrtf(n)) * inv[j];
        p = ((wm[j] >> cbit) & 1ull) ? p : 0.0f;
        outp[(size_t)j * 2048 + ni * 16] = p;
      }
    }
  }
}

// ---------------- out-proj + residual -> y (f32, in d_out) ----------------
__global__ __launch_bounds__(256) void gemm_oproj(
    const u16* __restrict__ A, const u16* __restrict__ Bt,
    const float* __restrict__ resR, const float* __restrict__ resI,
    float* __restrict__ outR, float* __restrict__ outI) {
  __shared__ u16 lA[128 * 64], lB[128 * 64];
  int t = threadIdx.x, lane = t & 63, wid = t >> 6;
  int c15 = lane & 15, g = lane >> 4, l7 = lane & 7;
  int brow = blockIdx.y * 128, bcol = blockIdx.x * 128;
  int sw0 = ((g ^ l7) << 3), sw1 = (((4 | g) ^ l7) << 3);
  int wr0 = (wid >> 1) * 64 + c15, wc0 = (wid & 1) * 64 + c15;
  const u16 *pA0 = lA + wr0 * 64 + sw0, *pA1 = lA + wr0 * 64 + sw1;
  const u16 *pB0 = lB + wc0 * 64 + sw0, *pB1 = lB + wc0 * 64 + sw1;
  f32x4 zero = {0.f, 0.f, 0.f, 0.f};
  f32x4 acc[4][4];
#pragma unroll
  for (int mi = 0; mi < 4; ++mi)
#pragma unroll
    for (int ni = 0; ni < 4; ++ni) acc[mi][ni] = zero;
  for (int kt = 0; kt < 1024; kt += 64) {
    glds128(A + (size_t)brow * 1024 + kt, 1024, lA, t);
    glds128(Bt + (size_t)bcol * 1024 + kt, 1024, lB, t);
    __syncthreads();
#pragma unroll
    for (int ks = 0; ks < 2; ++ks) {
      const u16* pa = ks ? pA1 : pA0;
      const u16* pb = ks ? pB1 : pB0;
      bf16x8 fa[4], fb[4];
#pragma unroll
      for (int i2 = 0; i2 < 4; ++i2) {
        fa[i2] = *(const bf16x8*)(pa + i2 * 1024);
        fb[i2] = *(const bf16x8*)(pb + i2 * 1024);
      }
#pragma unroll
      for (int mi = 0; mi < 4; ++mi)
#pragma unroll
        for (int ni = 0; ni < 4; ++ni)
          acc[mi][ni] = __builtin_amdgcn_mfma_f32_16x16x32_bf16(
              fa[mi], fb[ni], acc[mi][ni], 0, 0, 0);
    }
    __syncthreads();
  }
  int wrb = (wid >> 1) * 64, wcb = (wid & 1) * 64;
  int rj = g * 4, cj = c15;
#pragma unroll
  for (int mi = 0; mi < 4; ++mi)
#pragma unroll
    for (int ni = 0; ni < 4; ++ni)
#pragma unroll
      for (int j = 0; j < 4; ++j) {
        int row = brow + wrb + mi * 16 + rj + j;
        int col = bcol + wcb + ni * 16 + cj;
        float v = acc[mi][ni][j];
        if (col < 512)
          outR[(size_t)row * 512 + col] = v + resR[(size_t)row * 512 + col];
        else {
          int c2 = col - 512;
          outI[(size_t)row * 512 + c2] = v + resI[(size_t)row * 512 + c2];
        }
      }
}

// ---------------- complex layernorm ----------------
__global__ __launch_bounds__(256) void ln_reduce(const float* __restrict__ outR,
                                                 const float* __restrict__ outI,
                                                 float* __restrict__ stats) {
  int b = blockIdx.y;
  int t = threadIdx.x;
  size_t base = (size_t)b * 1048576 + (size_t)blockIdx.x * 2048;
  float s0 = 0.f, s1 = 0.f, s2 = 0.f, s3 = 0.f, s4 = 0.f;
#pragma unroll
  for (int p = 0; p < 8; ++p) {
    size_t e = base + p * 256 + t;
    float r = outR[e], i = outI[e];
    s0 += r; s1 += i; s2 += r * r; s3 += i * i; s4 += r * i;
  }
#pragma unroll
  for (int off = 32; off; off >>= 1) {
    s0 += __shfl_xor(s0, off); s1 += __shfl_xor(s1, off);
    s2 += __shfl_xor(s2, off); s3 += __shfl_xor(s3, off);
    s4 += __shfl_xor(s4, off);
  }
  __shared__ float red[4][5];
  if ((t & 63) == 0) {
    int w = t >> 6;
    red[w][0] = s0; red[w][1] = s1; red[w][2] = s2; red[w][3] = s3; red[w][4] = s4;
  }
  __syncthreads();
  if (t == 0) {
    float a0 = red[0][0] + red[1][0] + red[2][0] + red[3][0];
    float a1 = red[0][1] + red[1][1] + red[2][1] + red[3][1];
    float a2 = red[0][2] + red[1][2] + red[2][2] + red[3][2];
    float a3 = red[0][3] + red[1][3] + red[2][3] + red[3][3];
    float a4 = red[0][4] + red[1][4] + red[2][4] + red[3][4];
    atomicAdd(&stats[b * 8 + 0], a0);
    atomicAdd(&stats[b * 8 + 1], a1);
    atomicAdd(&stats[b * 8 + 2], a2);
    atomicAdd(&stats[b * 8 + 3], a3);
    atomicAdd(&stats[b * 8 + 4], a4);
  }
}

__global__ __launch_bounds__(256) void ln_apply(
    float* __restrict__ outR, float* __restrict__ outI,
    const float* __restrict__ stats,
    const float* __restrict__ lnwr, const float* __restrict__ lnwi,
    const float* __restrict__ lnbr, const float* __restrict__ lnbi) {
  int b = blockIdx.y;
  const float* st = stats + b * 8;
  float iN = 1.0f / 1048576.0f;
  float mr = st[0] * iN, mi = st[1] * iN;
  float Crr = st[2] * iN - mr * mr + 1e-6f;
  float Cii = st[3] * iN - mi * mi + 1e-6f;
  float Cri = st[4] * iN - mr * mi;
  float s = sqrtf(fmaxf(Crr * Cii - Cri * Cri, 0.f));
  float tt = sqrtf(Crr + Cii + 2.f * s);
  float inv = 1.0f / (s * tt);
  float Rrr = (Cii + s) * inv, Rii = (Crr + s) * inv, Rri = -Cri * inv;
  size_t e = ((size_t)blockIdx.x * 256 + threadIdx.x) * 4;
  size_t idx = (size_t)b * 1048576 + e;
  int d = (int)(e & 511);
  float4 r4 = *(float4*)(outR + idx);
  float4 i4 = *(float4*)(outI + idx);
  float4 wr = *(const float4*)(lnwr + d);
  float4 wi = *(const float4*)(lnwi + d);
  float4 br = *(const float4*)(lnbr + d);
  float4 bi = *(const float4*)(lnbi + d);
  float4 orr, oii;
#pragma unroll
  for (int j = 0; j < 4; ++j) {
    float r = ((&r4.x)[j]) - mr;
    float i = ((&i4.x)[j]) - mi;
    float nr = Rrr * r + Rri * i;
    float ni = Rii * i + Rri * r;
    (&orr.x)[j] = nr * (&wr.x)[j] - ni * (&wi.x)[j] + (&br.x)[j];
    (&oii.x)[j] = nr * (&wi.x)[j] + ni * (&wr.x)[j] + (&bi.x)[j];
  }
  *(float4*)(outR + idx) = orr;
  *(float4*)(outI + idx) = oii;
}

// ---------------- orchestration ----------------
extern "C" void kernel_launch(void* const* d_in, const int* in_sizes, int n_in,
                              void* d_out, int out_size, void* d_ws, size_t ws_size,
                              hipStream_t stream) {
  const float* q_r = (const float*)d_in[0];
  const float* q_i = (const float*)d_in[1];
  const float* k_r = (const float*)d_in[2];
  const float* k_i = (const float*)d_in[3];
  const float* v_r = (const float*)d_in[4];
  const float* v_i = (const float*)d_in[5];
  const float* wq_r = (const float*)d_in[6];
  const float* wq_i = (const float*)d_in[7];
  const float* wk_r = (const float*)d_in[8];
  const float* wk_i = (const float*)d_in[9];
  const float* wv_r = (const float*)d_in[10];
  const float* wv_i = (const float*)d_in[11];
  const float* wo_r = (const float*)d_in[12];
  const float* wo_i = (const float*)d_in[13];
  const float* ln_wr = (const float*)d_in[14];
  const float* ln_wi = (const float*)d_in[15];
  const float* ln_br = (const float*)d_in[16];
  const float* ln_bi = (const float*)d_in[17];
  const int* mask = (const int*)d_in[18];

  float* outR = (float*)d_out;
  float* outI = outR + 2097152;
  float* attn = outR + 4194304;  // final attn output (written once)

  char* ws = (char*)d_ws;
  u16* Aq = (u16*)ws;                    // 3 x 4194304 elems (packed A)
  u16* Bt = (u16*)(ws + 25165824);       // 4 x 1048576 elems (packed Bt)
  u16* Cq = (u16*)(ws + 33554432);       // 3 x 4194304 elems (proj out)
  u16* Ck = Cq + 4194304;
  u16* Cv = Cq + 8388608;
  u16* vt = Aq;                          // reuse A region after gemm_proj
  u16* Ao = (u16*)(ws + 58720256);       // 4194304 elems
  u64* mb = (u64*)(ws + 67108864);       // 131072 u64 (mask bits)
  float* stats = (float*)(ws + 69206016);
  float* invbuf = (float*)(ws + 69207040);  // 32768 floats

  prep<<<dim3(32768 + 6144 + 1024 + 1), 256, 0, stream>>>(
      q_r, q_i, k_r, k_i, v_r, v_i, wq_r, wq_i, wk_r, wk_i, wv_r, wv_i,
      wo_r, wo_i, mask, Aq, Bt, mb, stats);
  gemm_proj<<<dim3(8, 32, 3), 256, 0, stream>>>(Aq, Bt, Cq);
  pack_vt<<<dim3(64, 16), 256, 0, stream>>>(Cv, vt);
  fused_p1<<<dim3(32, 16), 256, 0, stream>>>(Cq, Ck, vt, mb, invbuf, Ao);
  attn_p2<<<dim3(128, 16), 256, 0, stream>>>(Cq, Ck, mb, invbuf, attn);
  gemm_oproj<<<dim3(8, 32), 256, 0, stream>>>(Ao, Bt + 3145728, q_r, q_i, outR, outI);
  ln_reduce<<<dim3(512, 2), 256, 0, stream>>>(outR, outI, stats);
  ln_apply<<<dim3(1024, 2), 256, 0, stream>>>(outR, outI, stats, ln_wr, ln_wi,
                                              ln_br, ln_bi);
}